// Round 7
// baseline (395.714 us; speedup 1.0000x reference)
//
#include <hip/hip_runtime.h>

#define HH 224
#define WW 224
#define PSD 112
#define NP 12544      // 112*112 patches per plane
#define NBG 1024      // B*G
#define NCH 28        // 4-patch chunks per patch row
#define NTASK (112 * NCH)   // 3136 tasks per plane
#define BLK 512       // 8 waves; 64 VGPR -> 4 blocks/CU -> 32 waves/CU (100%)

// Load L[0..8] = x[r][8t-1 .. 8t+7] (r assumed >= 0)
__device__ __forceinline__ void load_row9(const float* __restrict__ row,
                                          int t, float* L) {
    const int cb = 8 * t;
    L[0] = (t == 0) ? 0.f : row[cb - 1];
    float4 a = *reinterpret_cast<const float4*>(row + cb);
    float4 b = *reinterpret_cast<const float4*>(row + cb + 4);
    L[1] = a.x; L[2] = a.y; L[3] = a.z; L[4] = a.w;
    L[5] = b.x; L[6] = b.y; L[7] = b.z; L[8] = b.w;
}

__global__ __launch_bounds__(BLK, 8) void scann_k(
    const float* __restrict__ x,
    const float* __restrict__ Wq, const float* __restrict__ bq,
    const float* __restrict__ Wk, const float* __restrict__ bk,
    const float* __restrict__ Wv, const float* __restrict__ bv,
    const float* __restrict__ Wo, const float* __restrict__ bo,
    float* __restrict__ out) {
    const int bg = blockIdx.x;
    const int g = bg & 63;
    const float* __restrict__ xp = x + (size_t)bg * (HH * WW);
    const int tid = threadIdx.x;

    __shared__ float red[8][56];
    __shared__ float sh[54];     // gram: 45 upper-tri products + 9 sums
    __shared__ float TT[81];
    __shared__ float Qm_s[9];
    __shared__ float wsh[81];
    __shared__ float cf[10];

    // ---------------- Phase 1: gram accumulation ----------------
    float acc[45];
    float sm[9];
#pragma unroll
    for (int k = 0; k < 45; ++k) acc[k] = 0.f;
#pragma unroll
    for (int i = 0; i < 9; ++i) sm[i] = 0.f;

    for (int task = tid; task < NTASK; task += BLK) {
        const int ph = task / NCH;
        const int t = task - ph * NCH;
        const int r0 = 2 * ph - 1;
        float L[3][9];
#pragma unroll
        for (int kr = 0; kr < 3; ++kr) {
            const int r = r0 + kr;
            if (r < 0) {
#pragma unroll
                for (int j = 0; j < 9; ++j) L[kr][j] = 0.f;
            } else {
                load_row9(xp + r * WW, t, L[kr]);
            }
        }
#pragma unroll
        for (int u = 0; u < 4; ++u) {
            float v[9];
#pragma unroll
            for (int kh = 0; kh < 3; ++kh)
#pragma unroll
                for (int kw = 0; kw < 3; ++kw) v[3 * kh + kw] = L[kh][2 * u + kw];
            int k = 0;
#pragma unroll
            for (int i = 0; i < 9; ++i) {
                sm[i] += v[i];
#pragma unroll
                for (int j = i; j < 9; ++j) {
                    acc[k] += v[i] * v[j];
                    ++k;
                }
            }
        }
    }

    // ---------------- Phase 2: block reduction (8 waves) ----------------
    {
        const int lane = tid & 63;
        const int wv = tid >> 6;
#pragma unroll
        for (int k = 0; k < 45; ++k) {
            float v = acc[k];
#pragma unroll
            for (int off = 32; off; off >>= 1) v += __shfl_down(v, off, 64);
            if (lane == 0) red[wv][k] = v;
        }
#pragma unroll
        for (int i = 0; i < 9; ++i) {
            float v = sm[i];
#pragma unroll
            for (int off = 32; off; off >>= 1) v += __shfl_down(v, off, 64);
            if (lane == 0) red[wv][45 + i] = v;
        }
    }
    __syncthreads();
    if (tid < 54) {
        float s = 0.f;
#pragma unroll
        for (int w = 0; w < 8; ++w) s += red[w][tid];
        sh[tid] = s;
    }
    __syncthreads();

    // ---------------- Phase 3: attention-weight solve (9 threads) ----------
#define MIDX(i, j) (9 * (i) - (i) * ((i)-1) / 2 + ((j) - (i)))
#define MAT(i, j) ((i) <= (j) ? sh[MIDX(i, j)] : sh[MIDX(j, i)])
    if (tid < 9) {
        const int t = tid;
        const float* wqt = Wq + g * 81 + t * 9;
        float w[9];
#pragma unroll
        for (int j = 0; j < 9; ++j) w[j] = wqt[j];
        float q = 0.f;
#pragma unroll
        for (int j = 0; j < 9; ++j) q += w[j] * sh[45 + j];
        Qm_s[t] = q;
#pragma unroll
        for (int i = 0; i < 9; ++i) {
            float s = 0.f;
#pragma unroll
            for (int j = 0; j < 9; ++j) s += MAT(i, j) * w[j];
            TT[i * 9 + t] = s;
        }
    }
    __syncthreads();
    if (tid < 9) {
        const int s = tid;
        const float* wks = Wk + g * 81 + s * 9;
        float w[9];
#pragma unroll
        for (int i = 0; i < 9; ++i) w[i] = wks[i];
        float Km = 0.f;
#pragma unroll
        for (int i = 0; i < 9; ++i) Km += w[i] * sh[45 + i];
        const float bks = bk[g * 9 + s];
        float e[9];
#pragma unroll
        for (int t = 0; t < 9; ++t) {
            const float bqt = bq[g * 9 + t];
            float sum = bks * Qm_s[t] + bqt * Km + 12544.f * bks * bqt;
#pragma unroll
            for (int i = 0; i < 9; ++i) sum += w[i] * TT[i * 9 + t];
            e[t] = sum;
        }
        float mx = e[0];
#pragma unroll
        for (int t = 1; t < 9; ++t) mx = fmaxf(mx, e[t]);
        float ex[9], se = 0.f;
#pragma unroll
        for (int t = 0; t < 9; ++t) {
            ex[t] = expf(e[t] - mx);
            se += ex[t];
        }
        const float wos = Wo[g * 9 + s] / se;
#pragma unroll
        for (int t = 0; t < 9; ++t) wsh[s * 9 + t] = wos * ex[t];
    }
    __syncthreads();
    if (tid < 9) {
        const int j = tid;
        float weff[9];
#pragma unroll
        for (int t = 0; t < 9; ++t) {
            float s = 0.f;
#pragma unroll
            for (int s2 = 0; s2 < 9; ++s2) s += wsh[s2 * 9 + t];
            weff[t] = s;
        }
        float cj = 0.f;
#pragma unroll
        for (int t = 0; t < 9; ++t) cj += weff[t] * Wv[g * 81 + t * 9 + j];
        cf[j] = cj;
        if (j == 0) {
            float d = bo[g];
#pragma unroll
            for (int t = 0; t < 9; ++t) d += weff[t] * bv[g * 9 + t];
            cf[9] = d;
        }
    }
    __syncthreads();

    // ---------------- Phase 4: 3x3 stride-2 conv ----------------
    float cc[9];
#pragma unroll
    for (int j = 0; j < 9; ++j) cc[j] = cf[j];
    const float dd = cf[9];
    float* __restrict__ op = out + (size_t)bg * NP;

    for (int task = tid; task < NTASK; task += BLK) {
        const int ph = task / NCH;
        const int t = task - ph * NCH;
        const int r0 = 2 * ph - 1;
        float L[3][9];
#pragma unroll
        for (int kr = 0; kr < 3; ++kr) {
            const int r = r0 + kr;
            if (r < 0) {
#pragma unroll
                for (int j = 0; j < 9; ++j) L[kr][j] = 0.f;
            } else {
                load_row9(xp + r * WW, t, L[kr]);
            }
        }
        float o[4];
#pragma unroll
        for (int u = 0; u < 4; ++u) {
            float s = dd;
#pragma unroll
            for (int kh = 0; kh < 3; ++kh)
#pragma unroll
                for (int kw = 0; kw < 3; ++kw)
                    s += cc[3 * kh + kw] * L[kh][2 * u + kw];
            o[u] = s;
        }
        *reinterpret_cast<float4*>(op + ph * PSD + 4 * t) =
            make_float4(o[0], o[1], o[2], o[3]);
    }
}

extern "C" void kernel_launch(void* const* d_in, const int* in_sizes, int n_in,
                              void* d_out, int out_size, void* d_ws, size_t ws_size,
                              hipStream_t stream) {
    const float* x = (const float*)d_in[0];
    const float* Wq = (const float*)d_in[1];
    const float* bq = (const float*)d_in[2];
    const float* Wk = (const float*)d_in[3];
    const float* bk = (const float*)d_in[4];
    const float* Wv = (const float*)d_in[5];
    const float* bv = (const float*)d_in[6];
    const float* Wo = (const float*)d_in[7];
    const float* bo = (const float*)d_in[8];
    float* out = (float*)d_out;

    scann_k<<<NBG, BLK, 0, stream>>>(x, Wq, bq, Wk, bk, Wv, bv, Wo, bo, out);
}

// Round 8
// 87.651 us; speedup vs baseline: 4.5146x; 4.5146x over previous
//
#include <hip/hip_runtime.h>

#define HH 224
#define WW 224
#define PSD 112
#define NP 12544      // 112*112 patches per plane
#define NBG 1024      // B*G
#define NCH 28        // 4-patch chunks per patch row
#define NTASK (112 * NCH)   // 3136 tasks per plane

// ---- X-macro over the 54 gram outputs: (named scalar, MIDX-compatible idx) ----
#define ACC_LIST(X) \
  X(g00,0) X(g01,1) X(g02,2) X(g03,3) X(g04,4) X(g05,5) X(g06,6) X(g07,7) X(g08,8) \
  X(g11,9) X(g12,10) X(g13,11) X(g14,12) X(g15,13) X(g16,14) X(g17,15) X(g18,16) \
  X(g22,17) X(g23,18) X(g24,19) X(g25,20) X(g26,21) X(g27,22) X(g28,23) \
  X(g33,24) X(g34,25) X(g35,26) X(g36,27) X(g37,28) X(g38,29) \
  X(g44,30) X(g45,31) X(g46,32) X(g47,33) X(g48,34) \
  X(g55,35) X(g56,36) X(g57,37) X(g58,38) \
  X(g66,39) X(g67,40) X(g68,41) \
  X(g77,42) X(g78,43) \
  X(g88,44) \
  X(s0,45) X(s1,46) X(s2,47) X(s3,48) X(s4,49) X(s5,50) X(s6,51) X(s7,52) X(s8,53)

#define DECL0(V, I) float V = 0.f;
#define REDUCE1(V, I)                                    \
  {                                                      \
    float _v = V;                                        \
    _v += __shfl_down(_v, 32, 64);                       \
    _v += __shfl_down(_v, 16, 64);                       \
    _v += __shfl_down(_v, 8, 64);                        \
    _v += __shfl_down(_v, 4, 64);                        \
    _v += __shfl_down(_v, 2, 64);                        \
    _v += __shfl_down(_v, 1, 64);                        \
    if (lane == 0) red[wv][I] = _v;                      \
  }

// one 9-element patch: sums + all 45 upper-tri products (named scalars only)
#define GRAM_STEP(v0, v1, v2, v3, v4, v5, v6, v7, v8)                         \
  do {                                                                        \
    s0 += v0; s1 += v1; s2 += v2; s3 += v3; s4 += v4;                         \
    s5 += v5; s6 += v6; s7 += v7; s8 += v8;                                   \
    g00 += v0 * v0; g01 += v0 * v1; g02 += v0 * v2; g03 += v0 * v3;           \
    g04 += v0 * v4; g05 += v0 * v5; g06 += v0 * v6; g07 += v0 * v7;           \
    g08 += v0 * v8;                                                           \
    g11 += v1 * v1; g12 += v1 * v2; g13 += v1 * v3; g14 += v1 * v4;           \
    g15 += v1 * v5; g16 += v1 * v6; g17 += v1 * v7; g18 += v1 * v8;           \
    g22 += v2 * v2; g23 += v2 * v3; g24 += v2 * v4; g25 += v2 * v5;           \
    g26 += v2 * v6; g27 += v2 * v7; g28 += v2 * v8;                           \
    g33 += v3 * v3; g34 += v3 * v4; g35 += v3 * v5; g36 += v3 * v6;           \
    g37 += v3 * v7; g38 += v3 * v8;                                           \
    g44 += v4 * v4; g45 += v4 * v5; g46 += v4 * v6; g47 += v4 * v7;           \
    g48 += v4 * v8;                                                           \
    g55 += v5 * v5; g56 += v5 * v6; g57 += v5 * v7; g58 += v5 * v8;           \
    g66 += v6 * v6; g67 += v6 * v7; g68 += v6 * v8;                           \
    g77 += v7 * v7; g78 += v7 * v8;                                           \
    g88 += v8 * v8;                                                           \
  } while (0)

// Load 9 named scalars = x[r][8t-1 .. 8t+7]; zero==true -> all zeros (r < 0).
__device__ __forceinline__ void load9(const float* __restrict__ row, int t,
                                      bool zero, float& w0, float& w1,
                                      float& w2, float& w3, float& w4,
                                      float& w5, float& w6, float& w7,
                                      float& w8) {
    if (zero) {
        w0 = w1 = w2 = w3 = w4 = w5 = w6 = w7 = w8 = 0.f;
        return;
    }
    const int cb = 8 * t;
    w0 = (t == 0) ? 0.f : row[cb - 1];
    float4 a = *reinterpret_cast<const float4*>(row + cb);
    float4 b = *reinterpret_cast<const float4*>(row + cb + 4);
    w1 = a.x; w2 = a.y; w3 = a.z; w4 = a.w;
    w5 = b.x; w6 = b.y; w7 = b.z; w8 = b.w;
}

__global__ void __launch_bounds__(256)
__attribute__((amdgpu_waves_per_eu(4, 4)))
scann_k(const float* __restrict__ x,
        const float* __restrict__ Wq, const float* __restrict__ bq,
        const float* __restrict__ Wk, const float* __restrict__ bk,
        const float* __restrict__ Wv, const float* __restrict__ bv,
        const float* __restrict__ Wo, const float* __restrict__ bo,
        float* __restrict__ out) {
    const int bg = blockIdx.x;
    const int g = bg & 63;
    const float* __restrict__ xp = x + (size_t)bg * (HH * WW);
    const int tid = threadIdx.x;
    const int lane = tid & 63;
    const int wv = tid >> 6;

    __shared__ float red[4][56];
    __shared__ float sh[54];
    __shared__ float TT[81];
    __shared__ float Qm_s[9];
    __shared__ float wsh[81];
    __shared__ float cf[10];

    // ---------------- Phase 1: gram accumulation (all-scalar) ----------------
    ACC_LIST(DECL0)

    for (int task = tid; task < NTASK; task += 256) {
        const int ph = task / NCH;
        const int t = task - ph * NCH;
        const int r0 = 2 * ph - 1;
        float A0, A1, A2, A3, A4, A5, A6, A7, A8;
        float B0, B1, B2, B3, B4, B5, B6, B7, B8;
        float C0, C1, C2, C3, C4, C5, C6, C7, C8;
        load9(xp + r0 * WW, t, r0 < 0, A0, A1, A2, A3, A4, A5, A6, A7, A8);
        load9(xp + (r0 + 1) * WW, t, false, B0, B1, B2, B3, B4, B5, B6, B7, B8);
        load9(xp + (r0 + 2) * WW, t, false, C0, C1, C2, C3, C4, C5, C6, C7, C8);
        GRAM_STEP(A0, A1, A2, B0, B1, B2, C0, C1, C2);
        GRAM_STEP(A2, A3, A4, B2, B3, B4, C2, C3, C4);
        GRAM_STEP(A4, A5, A6, B4, B5, B6, C4, C5, C6);
        GRAM_STEP(A6, A7, A8, B6, B7, B8, C6, C7, C8);
    }

    // ---------------- Phase 2: block reduction ----------------
    ACC_LIST(REDUCE1)
    __syncthreads();
    if (tid < 54)
        sh[tid] = red[0][tid] + red[1][tid] + red[2][tid] + red[3][tid];
    __syncthreads();

    // ---------------- Phase 3: attention-weight solve (9 threads) ----------
#define MIDX(i, j) (9 * (i) - (i) * ((i)-1) / 2 + ((j) - (i)))
#define MAT(i, j) ((i) <= (j) ? sh[MIDX(i, j)] : sh[MIDX(j, i)])
    if (tid < 9) {
        const int t = tid;
        const float* wqt = Wq + g * 81 + t * 9;
        float w[9];
#pragma unroll
        for (int j = 0; j < 9; ++j) w[j] = wqt[j];
        float q = 0.f;
#pragma unroll
        for (int j = 0; j < 9; ++j) q += w[j] * sh[45 + j];
        Qm_s[t] = q;
#pragma unroll
        for (int i = 0; i < 9; ++i) {
            float s = 0.f;
#pragma unroll
            for (int j = 0; j < 9; ++j) s += MAT(i, j) * w[j];
            TT[i * 9 + t] = s;
        }
    }
    __syncthreads();
    if (tid < 9) {
        const int s = tid;
        const float* wks = Wk + g * 81 + s * 9;
        float w[9];
#pragma unroll
        for (int i = 0; i < 9; ++i) w[i] = wks[i];
        float Km = 0.f;
#pragma unroll
        for (int i = 0; i < 9; ++i) Km += w[i] * sh[45 + i];
        const float bks = bk[g * 9 + s];
        float e[9];
#pragma unroll
        for (int t = 0; t < 9; ++t) {
            const float bqt = bq[g * 9 + t];
            float sum = bks * Qm_s[t] + bqt * Km + 12544.f * bks * bqt;
#pragma unroll
            for (int i = 0; i < 9; ++i) sum += w[i] * TT[i * 9 + t];
            e[t] = sum;
        }
        float mx = e[0];
#pragma unroll
        for (int t = 1; t < 9; ++t) mx = fmaxf(mx, e[t]);
        float ex[9], se = 0.f;
#pragma unroll
        for (int t = 0; t < 9; ++t) {
            ex[t] = expf(e[t] - mx);
            se += ex[t];
        }
        const float wos = Wo[g * 9 + s] / se;
#pragma unroll
        for (int t = 0; t < 9; ++t) wsh[s * 9 + t] = wos * ex[t];
    }
    __syncthreads();
    if (tid < 9) {
        const int j = tid;
        float weff[9];
#pragma unroll
        for (int t = 0; t < 9; ++t) {
            float s = 0.f;
#pragma unroll
            for (int s2 = 0; s2 < 9; ++s2) s += wsh[s2 * 9 + t];
            weff[t] = s;
        }
        float cj = 0.f;
#pragma unroll
        for (int t = 0; t < 9; ++t) cj += weff[t] * Wv[g * 81 + t * 9 + j];
        cf[j] = cj;
        if (j == 0) {
            float d = bo[g];
#pragma unroll
            for (int t = 0; t < 9; ++t) d += weff[t] * bv[g * 9 + t];
            cf[9] = d;
        }
    }
    __syncthreads();

    // ---------------- Phase 4: 3x3 stride-2 conv ----------------
    float cc[9];
#pragma unroll
    for (int j = 0; j < 9; ++j) cc[j] = cf[j];
    const float dd = cf[9];
    float* __restrict__ op = out + (size_t)bg * NP;

    for (int task = tid; task < NTASK; task += 256) {
        const int ph = task / NCH;
        const int t = task - ph * NCH;
        const int r0 = 2 * ph - 1;
        float A0, A1, A2, A3, A4, A5, A6, A7, A8;
        float B0, B1, B2, B3, B4, B5, B6, B7, B8;
        float C0, C1, C2, C3, C4, C5, C6, C7, C8;
        load9(xp + r0 * WW, t, r0 < 0, A0, A1, A2, A3, A4, A5, A6, A7, A8);
        load9(xp + (r0 + 1) * WW, t, false, B0, B1, B2, B3, B4, B5, B6, B7, B8);
        load9(xp + (r0 + 2) * WW, t, false, C0, C1, C2, C3, C4, C5, C6, C7, C8);
        float o0 = dd + cc[0] * A0 + cc[1] * A1 + cc[2] * A2 + cc[3] * B0 +
                   cc[4] * B1 + cc[5] * B2 + cc[6] * C0 + cc[7] * C1 + cc[8] * C2;
        float o1 = dd + cc[0] * A2 + cc[1] * A3 + cc[2] * A4 + cc[3] * B2 +
                   cc[4] * B3 + cc[5] * B4 + cc[6] * C2 + cc[7] * C3 + cc[8] * C4;
        float o2 = dd + cc[0] * A4 + cc[1] * A5 + cc[2] * A6 + cc[3] * B4 +
                   cc[4] * B5 + cc[5] * B6 + cc[6] * C4 + cc[7] * C5 + cc[8] * C6;
        float o3 = dd + cc[0] * A6 + cc[1] * A7 + cc[2] * A8 + cc[3] * B6 +
                   cc[4] * B7 + cc[5] * B8 + cc[6] * C6 + cc[7] * C7 + cc[8] * C8;
        *reinterpret_cast<float4*>(op + ph * PSD + 4 * t) =
            make_float4(o0, o1, o2, o3);
    }
}

extern "C" void kernel_launch(void* const* d_in, const int* in_sizes, int n_in,
                              void* d_out, int out_size, void* d_ws, size_t ws_size,
                              hipStream_t stream) {
    const float* x = (const float*)d_in[0];
    const float* Wq = (const float*)d_in[1];
    const float* bq = (const float*)d_in[2];
    const float* Wk = (const float*)d_in[3];
    const float* bk = (const float*)d_in[4];
    const float* Wv = (const float*)d_in[5];
    const float* bv = (const float*)d_in[6];
    const float* Wo = (const float*)d_in[7];
    const float* bo = (const float*)d_in[8];
    float* out = (float*)d_out;

    scann_k<<<NBG, 256, 0, stream>>>(x, Wq, bq, Wk, bk, Wv, bv, Wo, bo, out);
}